// Round 3
// baseline (3650.563 us; speedup 1.0000x reference)
//
#include <hip/hip_runtime.h>

#define N_DIM 100000
#define M_DIM 200000
#define NNZ_A 2000000
#define NNZ_P 500000
#define NMSUM 300000
#define NM1   300001
#define CG_ITERS 20
#define TPB 256
#define NSLOT 512

#define GN_SLICES 1563          // ceil(N/64)
#define AR_SLICES 3125          // M/64
#define GN_CAP (1563L * 64 * 60)   // slice-max cap 60 (mean row len 25)
#define AR_CAP (3125L * 64 * 32)   // slice-max cap 32 (mean row len 10)

typedef unsigned long long ull;

// slots: sc[0]=xTPx, sc[1..3]=dd_t dots, sc[8..9]=rhs-FTmv dots,
// per-iter base 16+8*it: {d1,d2,e1,e2,pq, ftau}, gam[] at sc+432

__device__ __forceinline__ void blk_red_add(double v, double* dst) {
    __shared__ double sb[TPB];
    int tid = threadIdx.x;
    __syncthreads();
    sb[tid] = v;
    __syncthreads();
    for (int sh = TPB / 2; sh > 0; sh >>= 1) {
        if (tid < sh) sb[tid] += sb[tid + sh];
        __syncthreads();
    }
    if (tid == 0) atomicAdd(dst, sb[0]);
}

__device__ __forceinline__ ull pk(int idx, float v) {
    return (ull)(unsigned)idx | ((ull)__float_as_uint(v) << 32);
}

// SELL-64 row dot: coalesced nt pair stream + L2 gathers, uniform trip count
__device__ __forceinline__ double sell_dot(const ull* __restrict__ pair,
                                           const int* __restrict__ soff, int i,
                                           const double* __restrict__ vin) {
    int s = i >> 6;
    int o0 = soff[s], o1 = soff[s + 1];
    long base = (long)o0 + (i & 63);
    int trips = (o1 - o0) >> 6;
    double acc = 0.0;
    int j = 0;
    for (; j + 4 <= trips; j += 4) {
        ull e0 = __builtin_nontemporal_load(pair + base + (long)(j + 0) * 64);
        ull e1 = __builtin_nontemporal_load(pair + base + (long)(j + 1) * 64);
        ull e2 = __builtin_nontemporal_load(pair + base + (long)(j + 2) * 64);
        ull e3 = __builtin_nontemporal_load(pair + base + (long)(j + 3) * 64);
        double g0 = vin[(unsigned)e0];
        double g1 = vin[(unsigned)e1];
        double g2 = vin[(unsigned)e2];
        double g3 = vin[(unsigned)e3];
        acc += (double)__uint_as_float((unsigned)(e0 >> 32)) * g0;
        acc += (double)__uint_as_float((unsigned)(e1 >> 32)) * g1;
        acc += (double)__uint_as_float((unsigned)(e2 >> 32)) * g2;
        acc += (double)__uint_as_float((unsigned)(e3 >> 32)) * g3;
    }
    for (; j < trips; ++j) {
        ull e = __builtin_nontemporal_load(pair + base + (long)j * 64);
        acc += (double)__uint_as_float((unsigned)(e >> 32)) * vin[(unsigned)e];
    }
    return acc;
}

__device__ __forceinline__ double sell_dot_dval(const ull* __restrict__ pair,
                                                const float* __restrict__ dval,
                                                const int* __restrict__ soff, int i,
                                                const double* __restrict__ vin) {
    int s = i >> 6;
    int o0 = soff[s], o1 = soff[s + 1];
    long base = (long)o0 + (i & 63);
    int trips = (o1 - o0) >> 6;
    double acc = 0.0;
    for (int j = 0; j < trips; ++j) {
        long off = base + (long)j * 64;
        ull e = pair[off];
        acc += (double)dval[off] * vin[(unsigned)e];
    }
    return acc;
}

// ---------------- setup ----------------
__global__ __launch_bounds__(TPB) void k_init(double* sc, const float* y, const float* s,
                                              const float* x, double* mask_d, double* xpim,
                                              double* xcg,
                                              int* nP, int* cntGn, int* cntAr,
                                              int* curGn, int* curAr) {
    long i = (long)blockIdx.x * TPB + threadIdx.x;
    if (i < NSLOT) sc[i] = 0.0;
    if (i < M_DIM) {
        double v = (double)y[i] - (double)s[i];
        mask_d[i] = v > 0.0 ? 1.0 : 0.0;
        xpim[N_DIM + i] = v > 0.0 ? v : 0.0;   // pi_m
        cntAr[i] = 0;
        curAr[i] = 0;
    }
    if (i < N_DIM) {
        xpim[i] = (double)x[i];
        nP[i] = 0; cntGn[i] = 0; curGn[i] = 0;
    }
    if (i < NM1) xcg[i] = 0.0;
}

__global__ __launch_bounds__(TPB) void k_hist(const int* Ar, const int* Ac, const int* Pr,
                                              int* nP, int* cntGn, int* cntAr) {
    long k = (long)blockIdx.x * TPB + threadIdx.x;
    if (k < NNZ_A) {
        atomicAdd(&cntGn[Ac[k]], 1);
        atomicAdd(&cntAr[Ar[k]], 1);
    }
    if (k < NNZ_P) atomicAdd(&nP[Pr[k]], 1);
}

__global__ __launch_bounds__(TPB) void k_comb(const int* nP, int* cntGn) {
    int i = blockIdx.x * TPB + threadIdx.x;
    if (i < N_DIM) cntGn[i] += nP[i];
}

__global__ __launch_bounds__(TPB) void k_smax(const int* cnt, int nrows, int nslices, int* out64) {
    int s = blockIdx.x * TPB + threadIdx.x;
    if (s < nslices) {
        int lo = s * 64;
        int hi = lo + 64; if (hi > nrows) hi = nrows;
        int m = 0;
        for (int r0 = lo; r0 < hi; ++r0) m = max(m, cnt[r0]);
        out64[s] = m * 64;
    }
}

__global__ __launch_bounds__(TPB) void k_scan1(const int* cnt, int len, int* exc, int* blksum) {
    __shared__ int sb[TPB];
    int i = blockIdx.x * TPB + threadIdx.x;
    int v = (i < len) ? cnt[i] : 0;
    sb[threadIdx.x] = v;
    __syncthreads();
    for (int sh = 1; sh < TPB; sh <<= 1) {
        int t = (threadIdx.x >= sh) ? sb[threadIdx.x - sh] : 0;
        __syncthreads();
        sb[threadIdx.x] += t;
        __syncthreads();
    }
    if (i < len) exc[i] = sb[threadIdx.x] - v;
    if (threadIdx.x == TPB - 1) blksum[blockIdx.x] = sb[TPB - 1];
}

__global__ __launch_bounds__(1024) void k_scan2(int* blksum, int nb, int* total_out) {
    __shared__ int sb[1024];
    int t = threadIdx.x;
    int v = (t < nb) ? blksum[t] : 0;
    sb[t] = v;
    __syncthreads();
    for (int sh = 1; sh < 1024; sh <<= 1) {
        int x = (t >= sh) ? sb[t - sh] : 0;
        __syncthreads();
        sb[t] += x;
        __syncthreads();
    }
    if (t < nb) blksum[t] = sb[t] - v;
    if (t == nb - 1) *total_out = sb[t];
}

__global__ __launch_bounds__(TPB) void k_scan3(int* exc, const int* blksum, int len, int* cur) {
    int i = blockIdx.x * TPB + threadIdx.x;
    if (i < len) {
        int v = exc[i] + blksum[blockIdx.x];
        exc[i] = v;
        cur[i] = v;
    }
}

__global__ __launch_bounds__(TPB) void k_zero(ull* pairGn, float* dvalGn, const int* soffGn,
                                              ull* pairAr, float* dvalAr, const int* soffAr) {
    long k = (long)blockIdx.x * TPB + threadIdx.x;
    long tG = soffGn[GN_SLICES];
    long tA = soffAr[AR_SLICES];
    if (k < tG) { pairGn[k] = 0ull; dvalGn[k] = 0.0f; }
    if (k < tA) { pairAr[k] = 0ull; dvalAr[k] = 0.0f; }
}

// fill order: P entries FIRST per G_n row (prefix), then A^T entries
__global__ __launch_bounds__(TPB) void k_fillGnP(const int* Pr, const int* Pc, const float* Pv,
                                                 const float* dPv, const int* soffGn, int* curGn,
                                                 ull* pairGn, float* dvalGn) {
    long k = (long)blockIdx.x * TPB + threadIdx.x;
    if (k < NNZ_P) {
        int r0 = Pr[k];
        int j = atomicAdd(&curGn[r0], 1);
        long pos = (long)soffGn[r0 >> 6] + (long)j * 64 + (r0 & 63);
        pairGn[pos] = pk(Pc[k], Pv[k]);
        dvalGn[pos] = dPv[k];
    }
}
__global__ __launch_bounds__(TPB) void k_fillGnA(const int* Ar, const int* Ac, const float* Av,
                                                 const float* dAv, const int* soffGn, int* curGn,
                                                 ull* pairGn, float* dvalGn) {
    long k = (long)blockIdx.x * TPB + threadIdx.x;
    if (k < NNZ_A) {
        int r0 = Ac[k];
        int j = atomicAdd(&curGn[r0], 1);
        long pos = (long)soffGn[r0 >> 6] + (long)j * 64 + (r0 & 63);
        pairGn[pos] = pk(N_DIM + Ar[k], Av[k]);
        dvalGn[pos] = dAv[k];
    }
}
__global__ __launch_bounds__(TPB) void k_fillAr2(const int* Ar, const int* Ac, const float* Av,
                                                 const float* dAv, const int* soffAr, int* curAr,
                                                 ull* pairAr, float* dvalAr) {
    long k = (long)blockIdx.x * TPB + threadIdx.x;
    if (k < NNZ_A) {
        int r0 = Ar[k];
        int j = atomicAdd(&curAr[r0], 1);
        long pos = (long)soffAr[r0 >> 6] + (long)j * 64 + (r0 & 63);
        pairAr[pos] = pk(Ac[k], Av[k]);
        dvalAr[pos] = dAv[k];
    }
}

// fused: Px, dpx, c3, dd_n  (P entries are the nP-prefix of each G_n row)
__global__ __launch_bounds__(TPB) void k_setup_n(const ull* __restrict__ pairGn,
                                                 const float* __restrict__ dvalGn,
                                                 const int* __restrict__ soffGn,
                                                 const int* __restrict__ nP,
                                                 const double* __restrict__ xpim,
                                                 const float* __restrict__ q,
                                                 const float* __restrict__ dq,
                                                 double* Px, double* dpx, double* c3, double* dd) {
    int i = blockIdx.x * TPB + threadIdx.x;
    if (i >= N_DIM) return;
    int s = i >> 6;
    int o0 = soffGn[s], o1 = soffGn[s + 1];
    long base = (long)o0 + (i & 63);
    int trips = (o1 - o0) >> 6;
    int np = nP[i];
    double px = 0.0, dpxv = 0.0, sa = 0.0;
    for (int j = 0; j < trips; ++j) {
        long off = base + (long)j * 64;
        ull e = pairGn[off];
        float dv = dvalGn[off];
        double g = xpim[(unsigned)e];
        if (j < np) {
            px += (double)__uint_as_float((unsigned)(e >> 32)) * g;
            dpxv += (double)dv * g;
        } else {
            sa += (double)dv * g;
        }
    }
    Px[i] = px;
    dpx[i] = dpxv;
    c3[i] = (double)q[i] + 2.0 * px;
    dd[i] = dpxv + sa + (double)dq[i];
}

__global__ __launch_bounds__(TPB) void k_setup_m(const ull* __restrict__ pairAr,
                                                 const float* __restrict__ dvalAr,
                                                 const int* __restrict__ soffAr,
                                                 const double* __restrict__ xpim,
                                                 const float* __restrict__ db, double* dd) {
    int j = blockIdx.x * TPB + threadIdx.x;
    if (j >= M_DIM) return;
    double s = sell_dot_dval(pairAr, dvalAr, soffAr, j, xpim);
    dd[N_DIM + j] = -s + (double)db[j];
}

__global__ __launch_bounds__(TPB) void k_dot_fd(const float* a, const double* b, long len, double* dst) {
    long i = (long)blockIdx.x * TPB + threadIdx.x;
    double loc = 0.0;
    if (i < len) loc = (double)a[i] * b[i];
    blk_red_add(loc, dst);
}
__global__ __launch_bounds__(TPB) void k_dot_ff(const float* a, const float* b, long len, double* dst) {
    long i = (long)blockIdx.x * TPB + threadIdx.x;
    double loc = 0.0;
    if (i < len) loc = (double)a[i] * (double)b[i];
    blk_red_add(loc, dst);
}
__global__ __launch_bounds__(64) void k_dd_t(double* sc, double* dd) {
    if (threadIdx.x == 0) dd[NMSUM] = -sc[1] - sc[2] - sc[3];
}
// dd = -dd ; WC = [W_n ; -W_m]  (W = new dd)
__global__ __launch_bounds__(TPB) void k_negWC(double* dd, double* WC) {
    int i = blockIdx.x * TPB + threadIdx.x;
    if (i < NM1) {
        double nv = -dd[i];
        dd[i] = nv;
        if (i < N_DIM) WC[i] = nv;
        else if (i < NMSUM) WC[i] = -nv;
    }
}
__global__ __launch_bounds__(TPB) void k_rn(const ull* __restrict__ pairGn,
                                            const int* __restrict__ soffGn,
                                            const double* __restrict__ WC,
                                            const double* __restrict__ c3,
                                            const double* __restrict__ dd, double* r) {
    int i = blockIdx.x * TPB + threadIdx.x;
    if (i >= N_DIM) return;
    double s = sell_dot(pairGn, soffGn, i, WC);
    r[i] = s - c3[i] * dd[NMSUM];
}
__global__ __launch_bounds__(TPB) void k_rm(const ull* __restrict__ pairAr,
                                            const int* __restrict__ soffAr,
                                            const double* __restrict__ WC,
                                            const double* __restrict__ mask_d,
                                            const float* __restrict__ b,
                                            const double* __restrict__ dd, double* r) {
    int j = blockIdx.x * TPB + threadIdx.x;
    if (j >= M_DIM) return;
    double s = sell_dot(pairAr, soffAr, j, WC);
    double wt = dd[NMSUM];
    double tmv = s - (double)b[j] * wt;
    double wm = dd[N_DIM + j];
    r[N_DIM + j] = mask_d[j] * (tmv - wm) + wm;
}
__global__ __launch_bounds__(64) void k_ft_t(const double* e1, const double* e2, const double* xtpx,
                                             const double* W, double* U) {
    if (threadIdx.x == 0) U[NMSUM] = (*e1) + (*e2) + (*xtpx) * W[NMSUM];
}
__global__ __launch_bounds__(TPB) void k_cginit(const double* r, double* p, double* gam0) {
    int i = blockIdx.x * TPB + threadIdx.x;
    double loc = 0.0;
    if (i < NM1) { double v = r[i]; p[i] = v; loc = v * v; }
    blk_red_add(loc, gam0);
}

// ---------------- CG loop kernels ----------------
// K1: p-update + pum=[p_n; um] + d1,d2
__global__ __launch_bounds__(TPB) void k_iterA(const double* r, double* p,
                                               const double* mask_d, const double* c3,
                                               const float* b, double* pum,
                                               double* sc, int it) {
    long i = (long)blockIdx.x * TPB + threadIdx.x;
    double* gam = sc + 432;
    double* base = sc + 16 + 8 * it;
    double l1 = 0.0, l2 = 0.0;
    if (i < NM1) {
        double pn;
        if (it > 0) {
            double beta = gam[it] / gam[it - 1];
            pn = r[i] + beta * p[i];
            p[i] = pn;
        } else {
            pn = p[i];
        }
        if (i < N_DIM) {
            l1 = c3[i] * pn;
            pum[i] = pn;
        } else if (i < NMSUM) {
            int j = (int)(i - N_DIM);
            double u = mask_d[j] * pn;
            pum[i] = u;
            l2 = (double)b[j] * u;
        }
    }
    blk_red_add(l1, base);       // d1
    blk_red_add(l2, base + 1);   // d2
}

// K2: Fmv — SELL dots over pum; writes Fpc=[v_n; -v_m], base[5]=F_tau; e1,e2
__global__ __launch_bounds__(TPB) void k_fmv(const ull* __restrict__ pairGn, const int* __restrict__ soffGn,
                                             const ull* __restrict__ pairAr, const int* __restrict__ soffAr,
                                             const float* __restrict__ q, const float* __restrict__ b,
                                             const double* __restrict__ p, const double* __restrict__ pum,
                                             double* __restrict__ Fpc, double* sc, int it) {
    long i = (long)blockIdx.x * TPB + threadIdx.x;
    double* base = sc + 16 + 8 * it;
    double ut = p[NMSUM];
    double l1 = 0.0, l2 = 0.0;
    if (i < N_DIM) {
        double s = sell_dot(pairGn, soffGn, (int)i, pum);   // P p + A^T um
        double r1 = s + (double)q[i] * ut;
        double v = (r1 - p[i]) + p[i];
        Fpc[i] = v;
        l1 = (double)q[i] * v;
    } else if (i < NMSUM) {
        int j = (int)(i - N_DIM);
        double s = sell_dot(pairAr, soffAr, j, pum);        // A p_n
        double r2 = -s + (double)b[j] * ut;
        double v = (r2 - pum[i]) + p[i];
        Fpc[i] = -v;
        l2 = (double)b[j] * v;
    } else if (i == NMSUM) {
        double r3 = -base[0] - base[1] + sc[0] * ut;
        base[5] = (r3 - ut) + ut;                           // F_tau
    }
    blk_red_add(l1, base + 2);   // e1
    blk_red_add(l2, base + 3);   // e2
}

// K3: FTmv — SELL dots over Fpc; Ap + pq
__global__ __launch_bounds__(TPB) void k_ftmv(const ull* __restrict__ pairGn, const int* __restrict__ soffGn,
                                              const ull* __restrict__ pairAr, const int* __restrict__ soffAr,
                                              const float* __restrict__ b, const double* __restrict__ mask_d,
                                              const double* __restrict__ c3,
                                              const double* __restrict__ Fpc, const double* __restrict__ p,
                                              double* __restrict__ Ap, double* sc, int it) {
    long i = (long)blockIdx.x * TPB + threadIdx.x;
    double* base = sc + 16 + 8 * it;
    double wt = base[5];
    double l = 0.0;
    if (i < N_DIM) {
        double s = sell_dot(pairGn, soffGn, (int)i, Fpc);   // P Fp_n - A^T Fp_m
        double v = s - c3[i] * wt;
        Ap[i] = v;
        l = p[i] * v;
    } else if (i < NMSUM) {
        int j = (int)(i - N_DIM);
        double s = sell_dot(pairAr, soffAr, j, Fpc);        // A Fp_n
        double tmv = s - (double)b[j] * wt;
        double wm = -Fpc[i];
        double v = mask_d[j] * (tmv - wm) + wm;
        Ap[i] = v;
        l = p[i] * v;
    } else if (i == NMSUM) {
        double tt = base[2] + base[3] + sc[0] * wt;
        Ap[i] = tt;
        l = p[i] * tt;
    }
    blk_red_add(l, base + 4);   // pq
}

// K4: x,r update + gam[it+1]
__global__ __launch_bounds__(TPB) void k_upd(const double* p, const double* Ap,
                                             double* xcg, double* r, double* sc, int it) {
    long i = (long)blockIdx.x * TPB + threadIdx.x;
    double* gam = sc + 432;
    double* base = sc + 16 + 8 * it;
    double alpha = gam[it] / base[4];
    double l = 0.0;
    if (i < NM1) {
        xcg[i] += alpha * p[i];
        double rn = r[i] - alpha * Ap[i];
        r[i] = rn;
        l = rn * rn;
    }
    blk_red_add(l, &gam[it + 1]);
}

__global__ __launch_bounds__(TPB) void k_final(const double* xcg, const double* mask_d,
                                               const float* x, const float* y, const float* s,
                                               float* out) {
    int i = blockIdx.x * TPB + threadIdx.x;
    double dzt = xcg[NMSUM];
    if (i < N_DIM) {
        out[i] = (float)(xcg[i] - (double)x[i] * dzt);
    } else if (i < NMSUM) {
        int j = i - N_DIM;
        double dzm = xcg[N_DIM + j];
        double t = mask_d[j] * dzm;
        out[N_DIM + j] = (float)(t - (double)y[j] * dzt);
        out[N_DIM + M_DIM + j] = (float)(t - dzm - (double)s[j] * dzt);
    }
}

extern "C" void kernel_launch(void* const* d_in, const int* in_sizes, int n_in,
                              void* d_out, int out_size, void* d_ws, size_t ws_size,
                              hipStream_t stream) {
    const int*   Pr  = (const int*)d_in[0];
    const int*   Pc  = (const int*)d_in[1];
    const float* Pv  = (const float*)d_in[2];
    const int*   Ar  = (const int*)d_in[3];
    const int*   Ac  = (const int*)d_in[4];
    const float* Av  = (const float*)d_in[5];
    const float* q   = (const float*)d_in[6];
    const float* b   = (const float*)d_in[7];
    const float* x   = (const float*)d_in[8];
    const float* yv  = (const float*)d_in[9];
    const float* sv  = (const float*)d_in[10];
    const float* dPv = (const float*)d_in[11];
    const float* dAv = (const float*)d_in[12];
    const float* dq  = (const float*)d_in[13];
    const float* db  = (const float*)d_in[14];
    float* out = (float*)d_out;

    char* wp = (char*)d_ws;
    auto alloc = [&](size_t bytes) { char* r0 = wp; wp += (bytes + 255) & ~255ull; return r0; };

    double* sc     = (double*)alloc(NSLOT * 8);
    double* mask_d = (double*)alloc((size_t)M_DIM * 8);
    double* xpim   = (double*)alloc((size_t)NMSUM * 8);   // [x ; pi_m]
    double* Px     = (double*)alloc((size_t)N_DIM * 8);
    double* dpx    = (double*)alloc((size_t)N_DIM * 8);
    double* c3     = (double*)alloc((size_t)N_DIM * 8);
    double* dd     = (double*)alloc((size_t)NM1 * 8);
    double* r      = (double*)alloc((size_t)NM1 * 8);
    double* p      = (double*)alloc((size_t)NM1 * 8);
    double* xcg    = (double*)alloc((size_t)NM1 * 8);
    double* Ap     = (double*)alloc((size_t)NM1 * 8);
    double* pum    = (double*)alloc((size_t)NMSUM * 8);   // [p_n ; um]
    double* Fpc    = (double*)alloc((size_t)NMSUM * 8);   // [Fp_n ; -Fp_m]
    double* WC     = (double*)alloc((size_t)NMSUM * 8);   // [W_n ; -W_m]
    ull*   pairGn = (ull*)alloc((size_t)GN_CAP * 8);
    ull*   pairAr = (ull*)alloc((size_t)AR_CAP * 8);
    float* dvalGn = (float*)alloc((size_t)GN_CAP * 4);
    float* dvalAr = (float*)alloc((size_t)AR_CAP * 4);
    int*   nP     = (int*)alloc((size_t)N_DIM * 4);
    int*   cntGn  = (int*)alloc((size_t)N_DIM * 4);
    int*   cntAr  = (int*)alloc((size_t)M_DIM * 4);
    int*   curGn  = (int*)alloc((size_t)N_DIM * 4);
    int*   curAr  = (int*)alloc((size_t)M_DIM * 4);
    int*   smaxGn = (int*)alloc((size_t)GN_SLICES * 4);
    int*   smaxAr = (int*)alloc((size_t)AR_SLICES * 4);
    int*   soffGn = (int*)alloc((size_t)(GN_SLICES + 1) * 4);
    int*   soffAr = (int*)alloc((size_t)(AR_SLICES + 1) * 4);
    int*   blks   = (int*)alloc(1024 * 4);

    double* xtpx = sc + 0;
    double* gam  = sc + 432;

    auto g = [](long n) { return dim3((unsigned)((n + TPB - 1) / TPB)); };

    // ---- SELL build ----
    hipLaunchKernelGGL(k_init, g(NM1), dim3(TPB), 0, stream, sc, yv, sv, x, mask_d, xpim, xcg,
                       nP, cntGn, cntAr, curGn, curAr);
    hipLaunchKernelGGL(k_hist, g(NNZ_A), dim3(TPB), 0, stream, Ar, Ac, Pr, nP, cntGn, cntAr);
    hipLaunchKernelGGL(k_comb, g(N_DIM), dim3(TPB), 0, stream, nP, cntGn);
    hipLaunchKernelGGL(k_smax, g(GN_SLICES), dim3(TPB), 0, stream, cntGn, N_DIM, GN_SLICES, smaxGn);
    hipLaunchKernelGGL(k_smax, g(AR_SLICES), dim3(TPB), 0, stream, cntAr, M_DIM, AR_SLICES, smaxAr);

    auto scan = [&](int* cnt, int len, int* soff) {
        int nb = (len + TPB - 1) / TPB;
        hipLaunchKernelGGL(k_scan1, dim3((unsigned)nb), dim3(TPB), 0, stream, cnt, len, soff, blks);
        hipLaunchKernelGGL(k_scan2, dim3(1), dim3(1024), 0, stream, blks, nb, soff + len);
        hipLaunchKernelGGL(k_scan3, dim3((unsigned)nb), dim3(TPB), 0, stream, soff, blks, len, cnt);
    };
    scan(smaxGn, GN_SLICES, soffGn);
    scan(smaxAr, AR_SLICES, soffAr);

    hipLaunchKernelGGL(k_zero, g(AR_CAP > GN_CAP ? AR_CAP : GN_CAP), dim3(TPB), 0, stream,
                       pairGn, dvalGn, soffGn, pairAr, dvalAr, soffAr);
    hipLaunchKernelGGL(k_fillGnP, g(NNZ_P), dim3(TPB), 0, stream, Pr, Pc, Pv, dPv, soffGn, curGn, pairGn, dvalGn);
    hipLaunchKernelGGL(k_fillGnA, g(NNZ_A), dim3(TPB), 0, stream, Ar, Ac, Av, dAv, soffGn, curGn, pairGn, dvalGn);
    hipLaunchKernelGGL(k_fillAr2, g(NNZ_A), dim3(TPB), 0, stream, Ar, Ac, Av, dAv, soffAr, curAr, pairAr, dvalAr);

    // ---- setup math ----
    hipLaunchKernelGGL(k_setup_n, g(N_DIM), dim3(TPB), 0, stream, pairGn, dvalGn, soffGn, nP,
                       xpim, q, dq, Px, dpx, c3, dd);
    hipLaunchKernelGGL(k_setup_m, g(M_DIM), dim3(TPB), 0, stream, pairAr, dvalAr, soffAr, xpim, db, dd);
    hipLaunchKernelGGL(k_dot_fd, g(N_DIM), dim3(TPB), 0, stream, x, Px, (long)N_DIM, xtpx);
    hipLaunchKernelGGL(k_dot_ff, g(N_DIM), dim3(TPB), 0, stream, dq, x, (long)N_DIM, sc + 1);
    hipLaunchKernelGGL(k_dot_fd, g(M_DIM), dim3(TPB), 0, stream, db, xpim + N_DIM, (long)M_DIM, sc + 2);
    hipLaunchKernelGGL(k_dot_fd, g(N_DIM), dim3(TPB), 0, stream, x, dpx, (long)N_DIM, sc + 3);
    hipLaunchKernelGGL(k_dd_t, dim3(1), dim3(64), 0, stream, sc, dd);
    hipLaunchKernelGGL(k_negWC, g(NM1), dim3(TPB), 0, stream, dd, WC);
    hipLaunchKernelGGL(k_rn, g(N_DIM), dim3(TPB), 0, stream, pairGn, soffGn, WC, c3, dd, r);
    hipLaunchKernelGGL(k_rm, g(M_DIM), dim3(TPB), 0, stream, pairAr, soffAr, WC, mask_d, b, dd, r);
    hipLaunchKernelGGL(k_dot_fd, g(N_DIM), dim3(TPB), 0, stream, q, dd, (long)N_DIM, sc + 8);
    hipLaunchKernelGGL(k_dot_fd, g(M_DIM), dim3(TPB), 0, stream, b, dd + N_DIM, (long)M_DIM, sc + 9);
    hipLaunchKernelGGL(k_ft_t, dim3(1), dim3(64), 0, stream, sc + 8, sc + 9, xtpx, dd, r);
    hipLaunchKernelGGL(k_cginit, g(NM1), dim3(TPB), 0, stream, r, p, gam);

    // ---- 20 CG iterations, 4 launches each ----
    for (int it = 0; it < CG_ITERS; ++it) {
        hipLaunchKernelGGL(k_iterA, g(NM1), dim3(TPB), 0, stream, r, p, mask_d, c3, b, pum, sc, it);
        hipLaunchKernelGGL(k_fmv,   g(NM1), dim3(TPB), 0, stream, pairGn, soffGn, pairAr, soffAr,
                           q, b, p, pum, Fpc, sc, it);
        hipLaunchKernelGGL(k_ftmv,  g(NM1), dim3(TPB), 0, stream, pairGn, soffGn, pairAr, soffAr,
                           b, mask_d, c3, Fpc, p, Ap, sc, it);
        hipLaunchKernelGGL(k_upd,   g(NM1), dim3(TPB), 0, stream, p, Ap, xcg, r, sc, it);
    }

    hipLaunchKernelGGL(k_final, g(NMSUM), dim3(TPB), 0, stream, xcg, mask_d, x, yv, sv, out);
}